// Round 1
// baseline (399.605 us; speedup 1.0000x reference)
//
#include <hip/hip_runtime.h>

#define BB 128
#define TT 256
#define DDIM 64
#define ND 511        // number of anti-diagonals (2T-1)
#define NDP 512       // padded
#define BIGF 1e10f
#define GAM 0.01f
#define INVG 100.0f

// Diagonal-layout scratch: [b][diag][row], 64 MB each.
__device__ float g_D[(size_t)BB * NDP * TT];
__device__ float g_R[(size_t)BB * NDP * TT];
__device__ float g_sumE[BB];
__device__ float g_sumEw[BB];

// ---------------------------------------------------------------------------
// Kernel 1: pairwise squared distances, written in diagonal layout.
// grid (4,4,128), block 256. Each block: 64x64 output tile of batch b.
// ---------------------------------------------------------------------------
__global__ __launch_bounds__(256) void dist_kernel(const float* __restrict__ P,
                                                   const float* __restrict__ Q) {
    const int rt = blockIdx.x;   // row tile 0..3
    const int ct = blockIdx.y;   // col tile 0..3
    const int b  = blockIdx.z;
    const int tid = threadIdx.x;

    __shared__ float Pl[64][68];  // [k][local_row], padded stride
    __shared__ float Tl[64][68];  // [k][local_col]

    const float* Pbase = P + ((size_t)b * TT + rt * 64) * DDIM;
    const float* Qbase = Q + ((size_t)b * TT + ct * 64) * DDIM;

    // Load both 64x64 tiles (contiguous 16 KB each), transpose into [k][r].
#pragma unroll
    for (int it = 0; it < 4; ++it) {
        int e = (tid + it * 256) * 4;      // element index in tile
        int r = e >> 6;                    // /64
        int k = e & 63;
        float4 pv = *reinterpret_cast<const float4*>(Pbase + e);
        float4 qv = *reinterpret_cast<const float4*>(Qbase + e);
        Pl[k + 0][r] = pv.x; Pl[k + 1][r] = pv.y; Pl[k + 2][r] = pv.z; Pl[k + 3][r] = pv.w;
        Tl[k + 0][r] = qv.x; Tl[k + 1][r] = qv.y; Tl[k + 2][r] = qv.z; Tl[k + 3][r] = qv.w;
    }
    __syncthreads();

    const int r0 = (tid >> 4) * 4;   // local row of 4x4 microtile
    const int c0 = (tid & 15) * 4;   // local col

    float acc[4][4] = {};
#pragma unroll
    for (int k = 0; k < 64; ++k) {
        float4 p = *reinterpret_cast<const float4*>(&Pl[k][r0]);
        float4 t = *reinterpret_cast<const float4*>(&Tl[k][c0]);
        float pa[4] = {p.x, p.y, p.z, p.w};
        float ta[4] = {t.x, t.y, t.z, t.w};
#pragma unroll
        for (int a = 0; a < 4; ++a) {
#pragma unroll
            for (int c = 0; c < 4; ++c) {
                float df = pa[a] - ta[c];
                acc[a][c] = fmaf(df, df, acc[a][c]);
            }
        }
    }

    float* Dg = g_D + (size_t)b * NDP * TT;
#pragma unroll
    for (int a = 0; a < 4; ++a) {
#pragma unroll
        for (int c = 0; c < 4; ++c) {
            int i = rt * 64 + r0 + a;
            int j = ct * 64 + c0 + c;
            Dg[(size_t)(i + j) * TT + i] = acc[a][c];
        }
    }
}

// ---------------------------------------------------------------------------
// Kernel 2: soft-DTW forward wavefront scan. One block (256 thr) per batch.
// Thread i owns row i. Rotating mod-3 LDS diagonal buffers; 1 barrier/step.
// ---------------------------------------------------------------------------
__global__ __launch_bounds__(256) void fwd_kernel() {
    const int b = blockIdx.x;
    const int i = threadIdx.x;
    __shared__ float rb[3][TT];

    const float* Db = g_D + (size_t)b * NDP * TT;
    float* Rb       = g_R + (size_t)b * NDP * TT;

    rb[0][i] = BIGF; rb[1][i] = BIGF; rb[2][i] = BIGF;

    auto loadD = [&](int dd) -> float {
        int jj = dd - i;
        return (dd < ND && jj >= 0 && jj < TT) ? Db[(size_t)dd * TT + i] : 0.0f;
    };

    float rprev = BIGF;        // own R at previous diagonal (R[i][j-1])
    float dcur = loadD(0);
    float dnx1 = loadD(1);
    __syncthreads();

    for (int d = 0; d < ND; ++d) {
        float dnx2 = loadD(d + 2);   // depth-2 prefetch
        const int j = d - i;
        const bool valid = (j >= 0) & (j < TT);
        float rnew = BIGF;
        if (valid) {
            if (d == 0) {
                rnew = dcur;  // R[0][0] = D[0][0]
            } else {
                const float z1 = (i > 0 && j > 0) ? rb[(d + 1) % 3][i - 1] : BIGF; // R[i-1][j-1] (diag d-2)
                const float z2 = (i > 0)          ? rb[(d + 2) % 3][i - 1] : BIGF; // R[i-1][j]   (diag d-1)
                const float z3 = (j > 0)          ? rprev                  : BIGF; // R[i][j-1]   (diag d-1)
                float m = fminf(fminf(z1, z2), z3);
                float s = __expf((m - z1) * INVG) + __expf((m - z2) * INVG) + __expf((m - z3) * INVG);
                rnew = dcur + m - GAM * __logf(s);
            }
            Rb[(size_t)d * TT + i] = rnew;
        }
        rprev = rnew;
        rb[d % 3][i] = rnew;   // write class d%3 disjoint from read classes (d+1)%3,(d+2)%3
        dcur = dnx1; dnx1 = dnx2;
        __syncthreads();
    }
}

// ---------------------------------------------------------------------------
// Kernel 3: soft-DTW backward (E-matrix) wavefront scan + per-batch sums.
// E[i,j] = sum over valid successors s of E[s]*exp((R[s]-D[s]-R[i,j])/gamma).
// Rotating mod-4 LDS buffers for R, D, E; 1 barrier/step.
// ---------------------------------------------------------------------------
__global__ __launch_bounds__(256) void bwd_kernel() {
    const int b = blockIdx.x;
    const int i = threadIdx.x;
    __shared__ float Rl[4][TT];
    __shared__ float Dl[4][TT];
    __shared__ float El[4][TT];
    __shared__ float redE[256];
    __shared__ float redW[256];

    const float* Db = g_D + (size_t)b * NDP * TT;
    const float* Rb = g_R + (size_t)b * NDP * TT;

#pragma unroll
    for (int q = 0; q < 4; ++q) El[q][i] = 0.0f;

    auto loadR = [&](int dd) -> float {
        int jj = dd - i;
        return (dd >= 0 && jj >= 0 && jj < TT) ? Rb[(size_t)dd * TT + i] : BIGF;
    };
    auto loadDd = [&](int dd) -> float {
        int jj = dd - i;
        return (dd >= 0 && jj >= 0 && jj < TT) ? Db[(size_t)dd * TT + i] : 0.0f;
    };

    float sumE = 0.0f, sumEw = 0.0f;
    float rcur = loadR(ND - 1), dcur = loadDd(ND - 1);
    float rnx1 = loadR(ND - 2), dnx1 = loadDd(ND - 2);
    __syncthreads();  // El init visible

    for (int d = ND - 1; d >= 0; --d) {
        float rnx2 = loadR(d - 2), dnx2 = loadDd(d - 2);  // depth-2 prefetch
        Rl[d & 3][i] = rcur;
        Dl[d & 3][i] = dcur;
        __syncthreads();

        const int j = d - i;
        const bool valid = (j >= 0) & (j < TT);
        float E = 0.0f;
        if (valid) {
            if (d == ND - 1) {
                E = 1.0f;  // cell (T-1, T-1)
            } else {
                const int bp1 = (d + 1) & 3, bp2 = (d + 2) & 3;
                float acc = 0.0f;
                if (i + 1 < TT)   // successor (i+1, j) on diag d+1
                    acc += El[bp1][i + 1] * __expf((Rl[bp1][i + 1] - Dl[bp1][i + 1] - rcur) * INVG);
                if (j + 1 < TT)   // successor (i, j+1) on diag d+1
                    acc += El[bp1][i] * __expf((Rl[bp1][i] - Dl[bp1][i] - rcur) * INVG);
                if (i + 1 < TT && j + 1 < TT)  // successor (i+1, j+1) on diag d+2
                    acc += El[bp2][i + 1] * __expf((Rl[bp2][i + 1] - Dl[bp2][i + 1] - rcur) * INVG);
                E = acc;
            }
            const float dij = (float)(i - j);
            sumE += E;
            sumEw += E * dij * dij;   // omega scale applied in finalize
        }
        El[d & 3][i] = E;   // write class d&3 disjoint from read classes (d+1)&3,(d+2)&3
        rcur = rnx1; dcur = dnx1;
        rnx1 = rnx2; dnx1 = dnx2;
        // single barrier per step happens at top of next iteration (after RD write)
    }

    redE[i] = sumE;
    redW[i] = sumEw;
    __syncthreads();
    for (int s = 128; s > 0; s >>= 1) {
        if (i < s) { redE[i] += redE[i + s]; redW[i] += redW[i + s]; }
        __syncthreads();
    }
    if (i == 0) { g_sumE[b] = redE[0]; g_sumEw[b] = redW[0]; }
}

// ---------------------------------------------------------------------------
// Kernel 4: finalize scalar loss. 1 block, 128 threads (one per batch).
// ---------------------------------------------------------------------------
__global__ __launch_bounds__(128) void fin_kernel(float* __restrict__ out) {
    __shared__ float rs[128];
    __shared__ float rt2[128];
    const int b = threadIdx.x;

    const float rfin = g_R[((size_t)b * NDP + (ND - 1)) * TT + (TT - 1)];
    const float shape = rfin * (1.0f / (float)TT);

    const float sE  = g_sumE[b] * (1.0f / (float)TT);
    const float sEw = g_sumEw[b] * (1.0f / (float)TT) * (1.0f / (255.0f * 255.0f));
    const float temporal = sEw / fmaxf(sE, 1e-8f);

    rs[b] = shape;
    rt2[b] = temporal;
    __syncthreads();
    for (int s = 64; s > 0; s >>= 1) {
        if (b < s) { rs[b] += rs[b + s]; rt2[b] += rt2[b + s]; }
        __syncthreads();
    }
    if (b == 0) {
        out[0] = 0.5f * (rs[0] * (1.0f / (float)BB)) + 0.5f * (rt2[0] * (1.0f / (float)BB));
    }
}

extern "C" void kernel_launch(void* const* d_in, const int* in_sizes, int n_in,
                              void* d_out, int out_size, void* d_ws, size_t ws_size,
                              hipStream_t stream) {
    (void)in_sizes; (void)n_in; (void)out_size; (void)d_ws; (void)ws_size;
    const float* preds   = (const float*)d_in[0];
    const float* targets = (const float*)d_in[1];
    float* out = (float*)d_out;

    dist_kernel<<<dim3(4, 4, BB), 256, 0, stream>>>(preds, targets);
    fwd_kernel<<<BB, 256, 0, stream>>>();
    bwd_kernel<<<BB, 256, 0, stream>>>();
    fin_kernel<<<1, 128, 0, stream>>>(out);
}

// Round 2
// 342.656 us; speedup vs baseline: 1.1662x; 1.1662x over previous
//
#include <hip/hip_runtime.h>

#define BB 128
#define TT 256
#define DDIM 64
#define ND 511         // number of anti-diagonals (2T-1)
#define NDP 512        // padded (slot 511 = safe prefetch pad, stays zero)
#define BIGF 1e10f
#define KE 144.2695040889f     // 1/(gamma*ln2) = 100*log2(e)
#define GLN2 0.0069314718056f  // gamma*ln2

// Diagonal-layout scratch: [b][diag][row].
__device__ float  g_D [(size_t)BB * NDP * TT];   // 64 MiB
__device__ float2 g_RD[(size_t)BB * NDP * TT];   // 128 MiB: {R, (R-D)*KE}
__device__ float  g_sumE[BB];
__device__ float  g_sumEw[BB];

__device__ __forceinline__ float ex2(float x) {  // 2^x, raw HW trans op
    float r; asm("v_exp_f32 %0, %1" : "=v"(r) : "v"(x)); return r;
}
__device__ __forceinline__ float lg2(float x) {  // log2(x)
    float r; asm("v_log_f32 %0, %1" : "=v"(r) : "v"(x)); return r;
}

// ---------------------------------------------------------------------------
// Kernel 1: pairwise squared distances, written in diagonal layout.
// grid (4,4,128), block 256. Each block: 64x64 output tile of batch b.
// ---------------------------------------------------------------------------
__global__ __launch_bounds__(256) void dist_kernel(const float* __restrict__ P,
                                                   const float* __restrict__ Q) {
    const int rt = blockIdx.x;
    const int ct = blockIdx.y;
    const int b  = blockIdx.z;
    const int tid = threadIdx.x;

    __shared__ float Pl[64][68];
    __shared__ float Tl[64][68];

    const float* Pbase = P + ((size_t)b * TT + rt * 64) * DDIM;
    const float* Qbase = Q + ((size_t)b * TT + ct * 64) * DDIM;

#pragma unroll
    for (int it = 0; it < 4; ++it) {
        int e = (tid + it * 256) * 4;
        int r = e >> 6;
        int k = e & 63;
        float4 pv = *reinterpret_cast<const float4*>(Pbase + e);
        float4 qv = *reinterpret_cast<const float4*>(Qbase + e);
        Pl[k + 0][r] = pv.x; Pl[k + 1][r] = pv.y; Pl[k + 2][r] = pv.z; Pl[k + 3][r] = pv.w;
        Tl[k + 0][r] = qv.x; Tl[k + 1][r] = qv.y; Tl[k + 2][r] = qv.z; Tl[k + 3][r] = qv.w;
    }
    __syncthreads();

    const int r0 = (tid >> 4) * 4;
    const int c0 = (tid & 15) * 4;

    float acc[4][4] = {};
#pragma unroll
    for (int k = 0; k < 64; ++k) {
        float4 p = *reinterpret_cast<const float4*>(&Pl[k][r0]);
        float4 t = *reinterpret_cast<const float4*>(&Tl[k][c0]);
        float pa[4] = {p.x, p.y, p.z, p.w};
        float ta[4] = {t.x, t.y, t.z, t.w};
#pragma unroll
        for (int a = 0; a < 4; ++a)
#pragma unroll
            for (int c = 0; c < 4; ++c) {
                float df = pa[a] - ta[c];
                acc[a][c] = fmaf(df, df, acc[a][c]);
            }
    }

    float* Dg = g_D + (size_t)b * NDP * TT;
#pragma unroll
    for (int a = 0; a < 4; ++a)
#pragma unroll
        for (int c = 0; c < 4; ++c) {
            int i = rt * 64 + r0 + a;
            int j = ct * 64 + c0 + c;
            Dg[(size_t)(i + j) * TT + i] = acc[a][c];
        }
}

// ---------------------------------------------------------------------------
// Kernel 2: fused soft-DTW forward + backward. ONE WAVE (64 lanes) per batch.
// Lane owns rows 4*lane..4*lane+3. Neighbor exchange via shuffles only —
// no barriers, no LDS. Validity encoded in values: invalid R=BIGF,
// invalid AI=-1e12 => exp2 underflows to 0, so inner loops are branchless.
// ---------------------------------------------------------------------------
__global__ __launch_bounds__(64) void scan_kernel() {
    const int b = blockIdx.x;
    const int lane = threadIdx.x;
    const int row0 = lane << 2;

    const float* Db = g_D + (size_t)b * NDP * TT;
    float2* RDb = g_RD + (size_t)b * NDP * TT;

    auto loadD = [&](int dd) -> float4 {
        int di = dd > ND ? ND : dd;     // clamp into pad slot 511
        return *reinterpret_cast<const float4*>(Db + (size_t)di * TT + row0);
    };

    // ---------------- forward ----------------
    float R1[4], R2[4];   // rotating roles: diag d-1 / d-2
    {   // step 0: R[0][0] = D[0][0]
        float4 dq = loadD(0);
        float r00 = dq.x;
#pragma unroll
        for (int r = 0; r < 4; ++r) { R1[r] = BIGF; R2[r] = BIGF; }
        if (lane == 0) R1[0] = r00;
        float4 s0, s1;
        s0.x = (lane == 0) ? r00 : BIGF;
        s0.y = (lane == 0) ? 0.0f : -1e12f;
        s0.z = BIGF; s0.w = -1e12f;
        s1.x = BIGF; s1.y = -1e12f; s1.z = BIGF; s1.w = -1e12f;
        float4* sp = reinterpret_cast<float4*>(RDb + row0);
        sp[0] = s0; sp[1] = s1;
    }

    // fstep: B = diag d-1, A = diag d-2; writes diag d into A.
    auto fstep = [&](int d, const float4& dq, float (&A)[4], float (&B)[4]) {
        float r1n = __shfl_up(B[3], 1);
        float r2n = __shfl_up(A[3], 1);
        r1n = (lane == 0) ? BIGF : r1n;
        r2n = (lane == 0) ? BIGF : r2n;
        const float dv[4]  = {dq.x, dq.y, dq.z, dq.w};
        const float z1v[4] = {r2n, A[0], A[1], A[2]};   // R[row-1][j-1] (d-2)
        const float z2v[4] = {r1n, B[0], B[1], B[2]};   // R[row-1][j]   (d-1)
        float st[8];
#pragma unroll
        for (int r = 0; r < 4; ++r) {
            const float z1 = z1v[r];
            const float z2 = z2v[r];
            const float z3 = B[r];                       // R[row][j-1]  (d-1)
            const float m  = fminf(fminf(z1, z2), z3);
            const float mk = m * KE;
            const float s  = ex2(fmaf(z1, -KE, mk)) + ex2(fmaf(z2, -KE, mk))
                           + ex2(fmaf(z3, -KE, mk));
            const float rv = dv[r] + m - GLN2 * lg2(s);
            const int j = d - (row0 + r);
            const bool valid = (j >= 0) & (j < TT);
            const float rs = valid ? rv : BIGF;
            A[r] = rs;
            st[2 * r]     = rs;
            st[2 * r + 1] = valid ? (rv - dv[r]) * KE : -1e12f;
        }
        float4* sp = reinterpret_cast<float4*>(RDb + (size_t)d * TT + row0);
        sp[0] = make_float4(st[0], st[1], st[2], st[3]);
        sp[1] = make_float4(st[4], st[5], st[6], st[7]);
    };

    float4 q0 = loadD(1), q1 = loadD(2), q2 = loadD(3), q3 = loadD(4);
    for (int d = 1; d <= 505; d += 4) {   // 127 quads: diags 1..508
        fstep(d,     q0, R2, R1); q0 = loadD(d + 4);
        fstep(d + 1, q1, R1, R2); q1 = loadD(d + 5);
        fstep(d + 2, q2, R2, R1); q2 = loadD(d + 6);
        fstep(d + 3, q3, R1, R2); q3 = loadD(d + 7);
    }
    fstep(509, q0, R2, R1);
    fstep(510, q1, R1, R2);

    // make forward's RD stores visible to our own loads below
    asm volatile("s_waitcnt vmcnt(0)" ::: "memory");

    // ---------------- backward ----------------
    float E1a[4], A1a[4];   // diag d+1
    float E2a[4], A2a[4];   // diag d+2
    {
        const float4* p = reinterpret_cast<const float4*>(RDb + (size_t)510 * TT + row0);
        float4 lo = p[0], hi = p[1];
        A1a[0] = lo.y; A1a[1] = lo.w; A1a[2] = hi.y; A1a[3] = hi.w;
        E1a[0] = E1a[1] = E1a[2] = 0.0f;
        E1a[3] = (lane == 63) ? 1.0f : 0.0f;
#pragma unroll
        for (int r = 0; r < 4; ++r) { E2a[r] = 0.0f; A2a[r] = -1e12f; }
    }
    float sumE  = (lane == 63) ? 1.0f : 0.0f;   // cell (255,255), weight 0
    float sumEw = 0.0f;

    auto loadRD = [&](int dd, float4& lo, float4& hi) {
        int di = dd < 0 ? 0 : dd;
        const float4* p = reinterpret_cast<const float4*>(RDb + (size_t)di * TT + row0);
        lo = p[0]; hi = p[1];
    };

    // bstep: EB/AB = diag d+1, EA/AA = diag d+2; writes diag d into EA/AA.
    auto bstep = [&](int d, const float4& lo, const float4& hi,
                     float (&EA)[4], float (&AA)[4], float (&EB)[4], float (&AB)[4]) {
        float e1n = __shfl_down(EB[0], 1);
        float a1n = __shfl_down(AB[0], 1);
        float e2n = __shfl_down(EA[0], 1);
        float a2n = __shfl_down(AA[0], 1);
        e1n = (lane == 63) ? 0.0f    : e1n;
        a1n = (lane == 63) ? -1e12f  : a1n;
        e2n = (lane == 63) ? 0.0f    : e2n;
        a2n = (lane == 63) ? -1e12f  : a2n;
        const float rc[4] = {lo.x, lo.z, hi.x, hi.z};   // R  of diag d
        const float ac[4] = {lo.y, lo.w, hi.y, hi.w};   // AI of diag d
#pragma unroll
        for (int r = 0; r < 4; ++r) {
            const float mi  = rc[r] * KE;
            const float eA  = (r < 3) ? EB[r + 1] : e1n;   // (row+1, d+1)
            const float aAi = (r < 3) ? AB[r + 1] : a1n;
            const float eB_ = EB[r];                        // (row,   d+1)
            const float aBi = AB[r];
            const float eC  = (r < 3) ? EA[r + 1] : e2n;   // (row+1, d+2)
            const float aCi = (r < 3) ? AA[r + 1] : a2n;
            float E = eA * ex2(aAi - mi);
            E = fmaf(eB_, ex2(aBi - mi), E);
            E = fmaf(eC,  ex2(aCi - mi), E);
            EA[r] = E;          // diag d becomes new "d+1" after role swap
            AA[r] = ac[r];
            sumE += E;
            const float fw = (float)(2 * (row0 + r) - d);
            sumEw = fmaf(E * fw, fw, sumEw);
        }
    };

    float4 p0l, p0h, p1l, p1h, p2l, p2h, p3l, p3h;
    loadRD(509, p0l, p0h); loadRD(508, p1l, p1h);
    loadRD(507, p2l, p2h); loadRD(506, p3l, p3h);

    for (int d = 509; d >= 5; d -= 4) {   // 127 quads: diags 509..2
        bstep(d,     p0l, p0h, E2a, A2a, E1a, A1a); loadRD(d - 4, p0l, p0h);
        bstep(d - 1, p1l, p1h, E1a, A1a, E2a, A2a); loadRD(d - 5, p1l, p1h);
        bstep(d - 2, p2l, p2h, E2a, A2a, E1a, A1a); loadRD(d - 6, p2l, p2h);
        bstep(d - 3, p3l, p3h, E1a, A1a, E2a, A2a); loadRD(d - 7, p3l, p3h);
    }
    bstep(1, p0l, p0h, E2a, A2a, E1a, A1a);
    bstep(0, p1l, p1h, E1a, A1a, E2a, A2a);

    // wave reduction
#pragma unroll
    for (int off = 32; off; off >>= 1) {
        sumE  += __shfl_xor(sumE,  off);
        sumEw += __shfl_xor(sumEw, off);
    }
    if (lane == 0) { g_sumE[b] = sumE; g_sumEw[b] = sumEw; }
}

// ---------------------------------------------------------------------------
// Kernel 3: finalize scalar loss. 1 block, 128 threads (one per batch).
// ---------------------------------------------------------------------------
__global__ __launch_bounds__(128) void fin_kernel(float* __restrict__ out) {
    __shared__ float rs[128];
    __shared__ float rt2[128];
    const int b = threadIdx.x;

    const float rfin = g_RD[((size_t)b * NDP + (ND - 1)) * TT + (TT - 1)].x;
    const float shape = rfin * (1.0f / (float)TT);

    const float sE  = g_sumE[b]  * (1.0f / (float)TT);
    const float sEw = g_sumEw[b] * (1.0f / (float)TT) * (1.0f / (255.0f * 255.0f));
    const float temporal = sEw / fmaxf(sE, 1e-8f);

    rs[b]  = shape;
    rt2[b] = temporal;
    __syncthreads();
    for (int s = 64; s > 0; s >>= 1) {
        if (b < s) { rs[b] += rs[b + s]; rt2[b] += rt2[b + s]; }
        __syncthreads();
    }
    if (b == 0) {
        out[0] = 0.5f * (rs[0] * (1.0f / (float)BB)) + 0.5f * (rt2[0] * (1.0f / (float)BB));
    }
}

extern "C" void kernel_launch(void* const* d_in, const int* in_sizes, int n_in,
                              void* d_out, int out_size, void* d_ws, size_t ws_size,
                              hipStream_t stream) {
    (void)in_sizes; (void)n_in; (void)out_size; (void)d_ws; (void)ws_size;
    const float* preds   = (const float*)d_in[0];
    const float* targets = (const float*)d_in[1];
    float* out = (float*)d_out;

    dist_kernel<<<dim3(4, 4, BB), 256, 0, stream>>>(preds, targets);
    scan_kernel<<<BB, 64, 0, stream>>>();
    fin_kernel<<<1, 128, 0, stream>>>(out);
}

// Round 3
// 249.976 us; speedup vs baseline: 1.5986x; 1.3708x over previous
//
#include <hip/hip_runtime.h>

#define BB 128
#define TT 256
#define DDIM 64
#define ND 511         // diagonals 0..510; slots >=511 are pads
#define NDP 516        // padded slots per batch (pipeline dummies write 511,512)
#define BIGF 1e10f
#define KE 144.2695040889f     // 1/(gamma*ln2) = 100*log2(e)
#define GLN2 0.0069314718056f  // gamma*ln2

// Diagonal-layout scratch: [b][diag][row].
__device__ float  g_D [(size_t)BB * NDP * TT];
__device__ float2 g_RD[(size_t)BB * NDP * TT];   // {R, (R-D)*KE}
__device__ float  g_sumE[BB];
__device__ float  g_sumEw[BB];

__device__ __forceinline__ float ex2(float x) {
    float r; asm("v_exp_f32 %0, %1" : "=v"(r) : "v"(x)); return r;
}
__device__ __forceinline__ float lg2(float x) {
    float r; asm("v_log_f32 %0, %1" : "=v"(r) : "v"(x)); return r;
}

// ---------------------------------------------------------------------------
// Kernel 1: pairwise squared distances, written in diagonal layout.
// ---------------------------------------------------------------------------
__global__ __launch_bounds__(256) void dist_kernel(const float* __restrict__ P,
                                                   const float* __restrict__ Q) {
    const int rt = blockIdx.x;
    const int ct = blockIdx.y;
    const int b  = blockIdx.z;
    const int tid = threadIdx.x;

    __shared__ float Pl[64][68];
    __shared__ float Tl[64][68];

    const float* Pbase = P + ((size_t)b * TT + rt * 64) * DDIM;
    const float* Qbase = Q + ((size_t)b * TT + ct * 64) * DDIM;

#pragma unroll
    for (int it = 0; it < 4; ++it) {
        int e = (tid + it * 256) * 4;
        int r = e >> 6;
        int k = e & 63;
        float4 pv = *reinterpret_cast<const float4*>(Pbase + e);
        float4 qv = *reinterpret_cast<const float4*>(Qbase + e);
        Pl[k + 0][r] = pv.x; Pl[k + 1][r] = pv.y; Pl[k + 2][r] = pv.z; Pl[k + 3][r] = pv.w;
        Tl[k + 0][r] = qv.x; Tl[k + 1][r] = qv.y; Tl[k + 2][r] = qv.z; Tl[k + 3][r] = qv.w;
    }
    __syncthreads();

    const int r0 = (tid >> 4) * 4;
    const int c0 = (tid & 15) * 4;

    float acc[4][4] = {};
#pragma unroll
    for (int k = 0; k < 64; ++k) {
        float4 p = *reinterpret_cast<const float4*>(&Pl[k][r0]);
        float4 t = *reinterpret_cast<const float4*>(&Tl[k][c0]);
        float pa[4] = {p.x, p.y, p.z, p.w};
        float ta[4] = {t.x, t.y, t.z, t.w};
#pragma unroll
        for (int a = 0; a < 4; ++a)
#pragma unroll
            for (int c = 0; c < 4; ++c) {
                float df = pa[a] - ta[c];
                acc[a][c] = fmaf(df, df, acc[a][c]);
            }
    }

    float* Dg = g_D + (size_t)b * NDP * TT;
#pragma unroll
    for (int a = 0; a < 4; ++a)
#pragma unroll
        for (int c = 0; c < 4; ++c) {
            int i = rt * 64 + r0 + a;
            int j = ct * 64 + c0 + c;
            Dg[(size_t)(i + j) * TT + i] = acc[a][c];
        }
}

// ---------------------------------------------------------------------------
// Kernel 2: fused soft-DTW fwd+bwd. One wave per batch, 4 rows/lane.
// 16-step ping-pong groups, 8-deep register prefetch issued BEFORE the
// stores of the group (loads stay older than interleaved stores => their
// in-order vmcnt retirement is never blocked by store acks).
// ---------------------------------------------------------------------------
__global__ __launch_bounds__(64) void scan_kernel() {
    const int b = blockIdx.x;
    const int lane = threadIdx.x;
    const int row0 = lane << 2;

    const float* Db = g_D + (size_t)b * NDP * TT;
    float2* RDb = g_RD + (size_t)b * NDP * TT;

    auto loadD = [&](int dd) -> float4 {
        int di = dd > ND ? ND : dd;     // clamp into pad slot
        return *reinterpret_cast<const float4*>(Db + (size_t)di * TT + row0);
    };

    // ---------------- forward ----------------
    float R1[4], R2[4];

    float4 qa[8], qb[8];
#pragma unroll
    for (int k = 0; k < 8; ++k) qa[k] = loadD(1 + k);   // prime depth-8

    {   // step 0: R[0][0] = D[0][0]
        float4 dq = loadD(0);
        float r00 = dq.x;
#pragma unroll
        for (int r = 0; r < 4; ++r) { R1[r] = BIGF; R2[r] = BIGF; }
        if (lane == 0) R1[0] = r00;
        float4 s0, s1;
        s0.x = (lane == 0) ? r00 : BIGF;
        s0.y = (lane == 0) ? 0.0f : -1e12f;
        s0.z = BIGF; s0.w = -1e12f;
        s1.x = BIGF; s1.y = -1e12f; s1.z = BIGF; s1.w = -1e12f;
        float4* sp = reinterpret_cast<float4*>(RDb + row0);
        sp[0] = s0; sp[1] = s1;
    }

    // B = diag d-1, A = diag d-2; writes diag d into A.
    // Shuffle results are needed only by row 0 -> compute rows 1..3 first.
    auto fstep = [&](int d, const float4& dq, float (&A)[4], float (&B)[4]) {
        float r1n = __shfl_up(B[3], 1);       // R[row0-1] on diag d-1
        float r2n = __shfl_up(A[3], 1);       // R[row0-1] on diag d-2
        const float dv[4]  = {dq.x, dq.y, dq.z, dq.w};
        const float z1s[3] = {A[0], A[1], A[2]};
        const float z2s[3] = {B[0], B[1], B[2]};
        float st[8];
#pragma unroll
        for (int r = 1; r < 4; ++r) {
            const float z1 = z1s[r - 1];
            const float z2 = z2s[r - 1];
            const float z3 = B[r];
            const float m  = fminf(fminf(z1, z2), z3);
            const float mk = m * KE;
            const float s  = ex2(fmaf(z1, -KE, mk)) + ex2(fmaf(z2, -KE, mk))
                           + ex2(fmaf(z3, -KE, mk));
            const float rv = dv[r] + m - GLN2 * lg2(s);
            const int j = d - (row0 + r);
            const bool valid = (j >= 0) & (j < TT);
            A[r] = valid ? rv : BIGF;
            st[2 * r]     = A[r];
            st[2 * r + 1] = valid ? (rv - dv[r]) * KE : -1e12f;
        }
        {   // row 0 (uses shuffles)
            const float z1 = (lane == 0) ? BIGF : r2n;
            const float z2 = (lane == 0) ? BIGF : r1n;
            const float z3 = B[0];
            const float m  = fminf(fminf(z1, z2), z3);
            const float mk = m * KE;
            const float s  = ex2(fmaf(z1, -KE, mk)) + ex2(fmaf(z2, -KE, mk))
                           + ex2(fmaf(z3, -KE, mk));
            const float rv = dv[0] + m - GLN2 * lg2(s);
            const int j = d - row0;
            const bool valid = (j >= 0) & (j < TT);
            A[0] = valid ? rv : BIGF;
            st[0] = A[0];
            st[1] = valid ? (rv - dv[0]) * KE : -1e12f;
        }
        float4* sp = reinterpret_cast<float4*>(RDb + (size_t)d * TT + row0);
        sp[0] = make_float4(st[0], st[1], st[2], st[3]);
        sp[1] = make_float4(st[4], st[5], st[6], st[7]);
    };

#pragma unroll 1
    for (int g = 0; g < 32; ++g) {          // d = 1..512 (511,512 = pad dummies)
        const int d0 = 1 + g * 16;
#pragma unroll
        for (int k = 0; k < 8; ++k) qb[k] = loadD(d0 + 8 + k);
        __builtin_amdgcn_sched_barrier(0);
        fstep(d0 + 0, qa[0], R2, R1); fstep(d0 + 1, qa[1], R1, R2);
        fstep(d0 + 2, qa[2], R2, R1); fstep(d0 + 3, qa[3], R1, R2);
        fstep(d0 + 4, qa[4], R2, R1); fstep(d0 + 5, qa[5], R1, R2);
        fstep(d0 + 6, qa[6], R2, R1); fstep(d0 + 7, qa[7], R1, R2);
#pragma unroll
        for (int k = 0; k < 8; ++k) qa[k] = loadD(d0 + 16 + k);
        __builtin_amdgcn_sched_barrier(0);
        fstep(d0 + 8,  qb[0], R2, R1); fstep(d0 + 9,  qb[1], R1, R2);
        fstep(d0 + 10, qb[2], R2, R1); fstep(d0 + 11, qb[3], R1, R2);
        fstep(d0 + 12, qb[4], R2, R1); fstep(d0 + 13, qb[5], R1, R2);
        fstep(d0 + 14, qb[6], R2, R1); fstep(d0 + 15, qb[7], R1, R2);
    }

    asm volatile("s_waitcnt vmcnt(0)" ::: "memory");

    // ---------------- backward ----------------
    float E1a[4], A1a[4];   // diag d+1
    float E2a[4], A2a[4];   // diag d+2
    {
        const float4* p = reinterpret_cast<const float4*>(RDb + (size_t)510 * TT + row0);
        float4 lo = p[0], hi = p[1];
        A1a[0] = lo.y; A1a[1] = lo.w; A1a[2] = hi.y; A1a[3] = hi.w;
        E1a[0] = E1a[1] = E1a[2] = 0.0f;
        E1a[3] = (lane == 63) ? 1.0f : 0.0f;
#pragma unroll
        for (int r = 0; r < 4; ++r) { E2a[r] = 0.0f; A2a[r] = -1e12f; }
    }
    float sumE  = (lane == 63) ? 1.0f : 0.0f;
    float sumEw = 0.0f;

    auto loadRD = [&](int dd, float4& lo, float4& hi) {
        int di = dd < 0 ? 0 : dd;
        const float4* p = reinterpret_cast<const float4*>(RDb + (size_t)di * TT + row0);
        lo = p[0]; hi = p[1];
    };

    // EB/AB = diag d+1, EA/AA = diag d+2; writes diag d into EA/AA.
    // Shuffle results needed only by row 3 (already last).
    auto bstep = [&](int d, const float4& lo, const float4& hi,
                     float (&EA)[4], float (&AA)[4], float (&EB)[4], float (&AB)[4]) {
        float e1n = __shfl_down(EB[0], 1);
        float a1n = __shfl_down(AB[0], 1);
        float e2n = __shfl_down(EA[0], 1);
        float a2n = __shfl_down(AA[0], 1);
        const float rc[4] = {lo.x, lo.z, hi.x, hi.z};
        const float ac[4] = {lo.y, lo.w, hi.y, hi.w};
        float lE = 0.0f, lEw = 0.0f;
#pragma unroll
        for (int r = 0; r < 4; ++r) {
            const float mi  = rc[r] * KE;
            const float eA  = (r < 3) ? EB[r + 1] : ((lane == 63) ? 0.0f   : e1n);
            const float aAi = (r < 3) ? AB[r + 1] : ((lane == 63) ? -1e12f : a1n);
            const float eB_ = EB[r];
            const float aBi = AB[r];
            const float eC  = (r < 3) ? EA[r + 1] : ((lane == 63) ? 0.0f   : e2n);
            const float aCi = (r < 3) ? AA[r + 1] : ((lane == 63) ? -1e12f : a2n);
            float E = eA * ex2(aAi - mi);
            E = fmaf(eB_, ex2(aBi - mi), E);
            E = fmaf(eC,  ex2(aCi - mi), E);
            EA[r] = E;
            AA[r] = ac[r];
            lE += E;
            const float fw = (float)(2 * (row0 + r) - d);
            lEw = fmaf(E * fw, fw, lEw);
        }
        if (d >= 0) { sumE += lE; sumEw += lEw; }   // gate pipeline dummies
    };

    float4 al[8], ah[8], bl[8], bh[8];
#pragma unroll
    for (int k = 0; k < 8; ++k) loadRD(509 - k, al[k], ah[k]);

#pragma unroll 1
    for (int g = 0; g < 32; ++g) {          // d = 509..-2 (-1,-2 = gated dummies)
        const int d0 = 509 - g * 16;
#pragma unroll
        for (int k = 0; k < 8; ++k) loadRD(d0 - 8 - k, bl[k], bh[k]);
        __builtin_amdgcn_sched_barrier(0);
        bstep(d0 - 0, al[0], ah[0], E2a, A2a, E1a, A1a);
        bstep(d0 - 1, al[1], ah[1], E1a, A1a, E2a, A2a);
        bstep(d0 - 2, al[2], ah[2], E2a, A2a, E1a, A1a);
        bstep(d0 - 3, al[3], ah[3], E1a, A1a, E2a, A2a);
        bstep(d0 - 4, al[4], ah[4], E2a, A2a, E1a, A1a);
        bstep(d0 - 5, al[5], ah[5], E1a, A1a, E2a, A2a);
        bstep(d0 - 6, al[6], ah[6], E2a, A2a, E1a, A1a);
        bstep(d0 - 7, al[7], ah[7], E1a, A1a, E2a, A2a);
#pragma unroll
        for (int k = 0; k < 8; ++k) loadRD(d0 - 16 - k, al[k], ah[k]);
        __builtin_amdgcn_sched_barrier(0);
        bstep(d0 - 8,  bl[0], bh[0], E2a, A2a, E1a, A1a);
        bstep(d0 - 9,  bl[1], bh[1], E1a, A1a, E2a, A2a);
        bstep(d0 - 10, bl[2], bh[2], E2a, A2a, E1a, A1a);
        bstep(d0 - 11, bl[3], bh[3], E1a, A1a, E2a, A2a);
        bstep(d0 - 12, bl[4], bh[4], E2a, A2a, E1a, A1a);
        bstep(d0 - 13, bl[5], bh[5], E1a, A1a, E2a, A2a);
        bstep(d0 - 14, bl[6], bh[6], E2a, A2a, E1a, A1a);
        bstep(d0 - 15, bl[7], bh[7], E1a, A1a, E2a, A2a);
    }

#pragma unroll
    for (int off = 32; off; off >>= 1) {
        sumE  += __shfl_xor(sumE,  off);
        sumEw += __shfl_xor(sumEw, off);
    }
    if (lane == 0) { g_sumE[b] = sumE; g_sumEw[b] = sumEw; }
}

// ---------------------------------------------------------------------------
// Kernel 3: finalize scalar loss.
// ---------------------------------------------------------------------------
__global__ __launch_bounds__(128) void fin_kernel(float* __restrict__ out) {
    __shared__ float rs[128];
    __shared__ float rt2[128];
    const int b = threadIdx.x;

    const float rfin = g_RD[((size_t)b * NDP + (ND - 1)) * TT + (TT - 1)].x;
    const float shape = rfin * (1.0f / (float)TT);

    const float sE  = g_sumE[b]  * (1.0f / (float)TT);
    const float sEw = g_sumEw[b] * (1.0f / (float)TT) * (1.0f / (255.0f * 255.0f));
    const float temporal = sEw / fmaxf(sE, 1e-8f);

    rs[b]  = shape;
    rt2[b] = temporal;
    __syncthreads();
    for (int s = 64; s > 0; s >>= 1) {
        if (b < s) { rs[b] += rs[b + s]; rt2[b] += rt2[b + s]; }
        __syncthreads();
    }
    if (b == 0) {
        out[0] = 0.5f * (rs[0] * (1.0f / (float)BB)) + 0.5f * (rt2[0] * (1.0f / (float)BB));
    }
}

extern "C" void kernel_launch(void* const* d_in, const int* in_sizes, int n_in,
                              void* d_out, int out_size, void* d_ws, size_t ws_size,
                              hipStream_t stream) {
    (void)in_sizes; (void)n_in; (void)out_size; (void)d_ws; (void)ws_size;
    const float* preds   = (const float*)d_in[0];
    const float* targets = (const float*)d_in[1];
    float* out = (float*)d_out;

    dist_kernel<<<dim3(4, 4, BB), 256, 0, stream>>>(preds, targets);
    scan_kernel<<<BB, 64, 0, stream>>>();
    fin_kernel<<<1, 128, 0, stream>>>(out);
}

// Round 4
// 215.318 us; speedup vs baseline: 1.8559x; 1.1610x over previous
//
#include <hip/hip_runtime.h>

#define BB 128
#define TT 256
#define DDIM 64
#define ND 511
#define NDP 516
#define BIGF 1e10f
#define NEGB -1e12f
#define KE 144.2695040889f     // 1/(gamma*ln2)
#define GLN2 0.0069314718056f  // gamma*ln2

// Diagonal-layout scratch: [b][diag][row].
__device__ float  g_D [(size_t)BB * NDP * TT];
__device__ float2 g_RD[(size_t)BB * NDP * TT];   // {R, (R-D)*KE}
__device__ float  g_sumE[BB];
__device__ float  g_sumEw[BB];

__device__ __forceinline__ float ex2(float x){ float r; asm("v_exp_f32 %0, %1":"=v"(r):"v"(x)); return r; }
__device__ __forceinline__ float lg2(float x){ float r; asm("v_log_f32 %0, %1":"=v"(r):"v"(x)); return r; }
__device__ __forceinline__ float min3f(float a,float b,float c){ float r; asm("v_min3_f32 %0,%1,%2,%3":"=v"(r):"v"(a),"v"(b),"v"(c)); return r; }
__device__ __forceinline__ float med3f(float a,float b,float c){ float r; asm("v_med3_f32 %0,%1,%2,%3":"=v"(r):"v"(a),"v"(b),"v"(c)); return r; }
__device__ __forceinline__ float max3f(float a,float b,float c){ float r; asm("v_max3_f32 %0,%1,%2,%3":"=v"(r):"v"(a),"v"(b),"v"(c)); return r; }

// ---------------------------------------------------------------------------
// Kernel 1: pairwise squared distances, written in diagonal layout.
// ---------------------------------------------------------------------------
__global__ __launch_bounds__(256) void dist_kernel(const float* __restrict__ P,
                                                   const float* __restrict__ Q) {
    const int rt = blockIdx.x;
    const int ct = blockIdx.y;
    const int b  = blockIdx.z;
    const int tid = threadIdx.x;

    __shared__ float Pl[64][68];
    __shared__ float Tl[64][68];

    const float* Pbase = P + ((size_t)b * TT + rt * 64) * DDIM;
    const float* Qbase = Q + ((size_t)b * TT + ct * 64) * DDIM;

#pragma unroll
    for (int it = 0; it < 4; ++it) {
        int e = (tid + it * 256) * 4;
        int r = e >> 6;
        int k = e & 63;
        float4 pv = *reinterpret_cast<const float4*>(Pbase + e);
        float4 qv = *reinterpret_cast<const float4*>(Qbase + e);
        Pl[k + 0][r] = pv.x; Pl[k + 1][r] = pv.y; Pl[k + 2][r] = pv.z; Pl[k + 3][r] = pv.w;
        Tl[k + 0][r] = qv.x; Tl[k + 1][r] = qv.y; Tl[k + 2][r] = qv.z; Tl[k + 3][r] = qv.w;
    }
    __syncthreads();

    const int r0 = (tid >> 4) * 4;
    const int c0 = (tid & 15) * 4;

    float acc[4][4] = {};
#pragma unroll
    for (int k = 0; k < 64; ++k) {
        float4 p = *reinterpret_cast<const float4*>(&Pl[k][r0]);
        float4 t = *reinterpret_cast<const float4*>(&Tl[k][c0]);
        float pa[4] = {p.x, p.y, p.z, p.w};
        float ta[4] = {t.x, t.y, t.z, t.w};
#pragma unroll
        for (int a = 0; a < 4; ++a)
#pragma unroll
            for (int c = 0; c < 4; ++c) {
                float df = pa[a] - ta[c];
                acc[a][c] = fmaf(df, df, acc[a][c]);
            }
    }

    float* Dg = g_D + (size_t)b * NDP * TT;
#pragma unroll
    for (int a = 0; a < 4; ++a)
#pragma unroll
        for (int c = 0; c < 4; ++c) {
            int i = rt * 64 + r0 + a;
            int j = ct * 64 + c0 + c;
            Dg[(size_t)(i + j) * TT + i] = acc[a][c];
        }
}

// ---------------------------------------------------------------------------
// Kernel 2: fused soft-DTW fwd+bwd. 4 waves per batch, 1 row per lane.
// Waves skewed by 16 diagonals; boundary row exchanged via 64-slot LDS ring;
// one __syncthreads per 16 steps. Validity value-encoded (BIG / -1e12).
// ---------------------------------------------------------------------------
__global__ __launch_bounds__(256) void scan_kernel() {
    const int b    = blockIdx.x;
    const int tid  = threadIdx.x;
    const int w    = tid >> 6;
    const int lane = tid & 63;
    const int r    = tid;                 // global row 0..255

    const float* Db  = g_D  + (size_t)b * NDP * TT;
    float2*      RDb = g_RD + (size_t)b * NDP * TT;

    __shared__ float  fring[64][4];
    __shared__ float2 bring[64][4];
    __shared__ float  redE[4], redW[4];

    fring[tid >> 2][tid & 3] = BIGF;
    bring[tid >> 2][tid & 3] = make_float2(0.0f, NEGB);
    __syncthreads();

    // ---------------- forward: wave w at phase p computes diag d = p - 16w --
    const int skew = w << 4;
    float rp1 = BIGF, rp2 = BIGF;         // own R at diag d-1, d-2

    auto loadDf = [&](int p) -> float {
        int d = p - skew;
        d = d < 0 ? 0 : (d > 510 ? 510 : d);
        return Db[(size_t)d * TT + r];
    };

    const int wiF = (w == 0) ? 0 : (w - 1);

    auto fstep = [&](int d, float dv) {
        float up1 = __shfl_up(rp1, 1);    // R[r-1][d-1]
        float up2 = __shfl_up(rp2, 1);    // R[r-1][d-2]
        float b1 = fring[(d - 1) & 63][wiF];
        float b2 = fring[(d - 2) & 63][wiF];
        if (w == 0) { b1 = BIGF; b2 = BIGF; }
        if (lane == 0) { up1 = b1; up2 = b2; }
        const float z1 = up2, z2 = up1, z3 = rp1;
        const float m  = min3f(z1, z2, z3);
        const float md = med3f(z1, z2, z3);
        const float mx = max3f(z1, z2, z3);
        const float s  = 1.0f + ex2((m - md) * KE) + ex2((m - mx) * KE);
        float rv = dv + m - GLN2 * lg2(s);
        if (d == 0) rv = dv;              // R[0][0] = D[0][0] (only r==0 valid)
        const int j = d - r;
        const bool valid = (j >= 0) & (j < TT) & (d >= 0) & (d <= 510);
        const float Rn = valid ? rv : BIGF;
        const float An = valid ? (rv - dv) * KE : NEGB;
        rp2 = rp1; rp1 = Rn;
        if (lane == 63) fring[d & 63][w] = Rn;   // value already gated
        const int sd = (d >= 0 && d <= 510) ? d : (512 + (d & 3));
        RDb[(size_t)sd * TT + r] = make_float2(Rn, An);
    };

    {
        float qa[16], qb[16];
#pragma unroll
        for (int k = 0; k < 16; ++k) qa[k] = loadDf(k);
#pragma unroll 1
        for (int g = 0; g < 18; ++g) {        // 576 phases total
            const int p0 = g * 32;
#pragma unroll
            for (int k = 0; k < 16; ++k) qb[k] = loadDf(p0 + 16 + k);
            __builtin_amdgcn_sched_barrier(0);
#pragma unroll
            for (int s2 = 0; s2 < 16; ++s2) fstep(p0 + s2 - skew, qa[s2]);
            __syncthreads();
#pragma unroll
            for (int k = 0; k < 16; ++k) qa[k] = loadDf(p0 + 32 + k);
            __builtin_amdgcn_sched_barrier(0);
#pragma unroll
            for (int s2 = 0; s2 < 16; ++s2) fstep(p0 + 16 + s2 - skew, qb[s2]);
            __syncthreads();
        }
    }

    asm volatile("s_waitcnt vmcnt(0)" ::: "memory");  // own fwd stores visible

    // ---------------- backward: wave w at phase p computes d = 509+16(3-w)-p
    float e1, a1, e2, a2;                 // state for diag d+1 / d+2
    {
        float2 v = RDb[(size_t)510 * TT + r];
        a1 = v.y;
        e1 = (r == 255) ? 1.0f : 0.0f;
        e2 = 0.0f; a2 = NEGB;
    }
    float sumE  = (r == 255) ? 1.0f : 0.0f;   // seed cell (255,255), weight 0
    float sumEw = 0.0f;

    const int bskew = (3 - w) << 4;
    auto loadRD = [&](int p) -> float2 {
        int d = 509 + bskew - p;
        d = d < 0 ? 0 : (d > 510 ? 510 : d);
        return RDb[(size_t)d * TT + r];
    };
    const int wiB = (w == 0) ? 3 : (w - 1);   // my write column (col 3 unused)
    const int wiR = (w < 3) ? w : 0;          // my read column (w==3 uses consts)

    auto bstep = [&](int d, float2 rdv) {
        float de1 = __shfl_down(e1, 1);   // E[r+1][d+1]
        float da1 = __shfl_down(a1, 1);
        float de2 = __shfl_down(e2, 1);   // E[r+1][d+2]
        float da2 = __shfl_down(a2, 1);
        float2 r1 = bring[(d + 1) & 63][wiR];
        float2 r2 = bring[(d + 2) & 63][wiR];
        if (w == 3) { r1 = make_float2(0.0f, NEGB); r2 = make_float2(0.0f, NEGB); }
        if (lane == 63) { de1 = r1.x; da1 = r1.y; de2 = r2.x; da2 = r2.y; }
        const float mi = rdv.x * KE;
        const float ac = rdv.y;
        float E = de1 * ex2(da1 - mi);
        E = fmaf(e1, ex2(a1 - mi), E);
        E = fmaf(de2, ex2(da2 - mi), E);
        const bool lead = (d > 509);               // leading dummy: hold state
        const bool real = (d >= 0) && (d <= 509);
        float ne2 = lead ? e2 : e1,  na2 = lead ? a2 : a1;
        float ne1 = lead ? e1 : E,   na1 = lead ? a1 : ac;
        e1 = ne1; a1 = na1; e2 = ne2; a2 = na2;
        const float Ea = real ? E : 0.0f;
        sumE += Ea;
        const float fw = (float)(2 * r - d);
        sumEw = fmaf(Ea * fw, fw, sumEw);
        float2 wv = real ? make_float2(E, ac) : make_float2(0.0f, NEGB);
        if (lane == 0) bring[d & 63][wiB] = wv;
    };

    {
        float2 ra[16], rb[16];
#pragma unroll
        for (int k = 0; k < 16; ++k) ra[k] = loadRD(k);
#pragma unroll 1
        for (int g = 0; g < 18; ++g) {
            const int p0 = g * 32;
#pragma unroll
            for (int k = 0; k < 16; ++k) rb[k] = loadRD(p0 + 16 + k);
            __builtin_amdgcn_sched_barrier(0);
#pragma unroll
            for (int s2 = 0; s2 < 16; ++s2) bstep(509 + bskew - (p0 + s2), ra[s2]);
            __syncthreads();
#pragma unroll
            for (int k = 0; k < 16; ++k) ra[k] = loadRD(p0 + 32 + k);
            __builtin_amdgcn_sched_barrier(0);
#pragma unroll
            for (int s2 = 0; s2 < 16; ++s2) bstep(509 + bskew - (p0 + 16 + s2), rb[s2]);
            __syncthreads();
        }
    }

    // reduction: wave-local shuffles, then 4 partials via LDS
#pragma unroll
    for (int off = 32; off; off >>= 1) {
        sumE  += __shfl_xor(sumE,  off);
        sumEw += __shfl_xor(sumEw, off);
    }
    if (lane == 0) { redE[w] = sumE; redW[w] = sumEw; }
    __syncthreads();
    if (tid == 0) {
        g_sumE[b]  = redE[0] + redE[1] + redE[2] + redE[3];
        g_sumEw[b] = redW[0] + redW[1] + redW[2] + redW[3];
    }
}

// ---------------------------------------------------------------------------
// Kernel 3: finalize scalar loss.
// ---------------------------------------------------------------------------
__global__ __launch_bounds__(128) void fin_kernel(float* __restrict__ out) {
    __shared__ float rs[128];
    __shared__ float rt2[128];
    const int b = threadIdx.x;

    const float rfin = g_RD[((size_t)b * NDP + (ND - 1)) * TT + (TT - 1)].x;
    const float shape = rfin * (1.0f / (float)TT);

    const float sE  = g_sumE[b]  * (1.0f / (float)TT);
    const float sEw = g_sumEw[b] * (1.0f / (float)TT) * (1.0f / (255.0f * 255.0f));
    const float temporal = sEw / fmaxf(sE, 1e-8f);

    rs[b]  = shape;
    rt2[b] = temporal;
    __syncthreads();
    for (int s = 64; s > 0; s >>= 1) {
        if (b < s) { rs[b] += rs[b + s]; rt2[b] += rt2[b + s]; }
        __syncthreads();
    }
    if (b == 0) {
        out[0] = 0.5f * (rs[0] * (1.0f / (float)BB)) + 0.5f * (rt2[0] * (1.0f / (float)BB));
    }
}

extern "C" void kernel_launch(void* const* d_in, const int* in_sizes, int n_in,
                              void* d_out, int out_size, void* d_ws, size_t ws_size,
                              hipStream_t stream) {
    (void)in_sizes; (void)n_in; (void)out_size; (void)d_ws; (void)ws_size;
    const float* preds   = (const float*)d_in[0];
    const float* targets = (const float*)d_in[1];
    float* out = (float*)d_out;

    dist_kernel<<<dim3(4, 4, BB), 256, 0, stream>>>(preds, targets);
    scan_kernel<<<BB, 256, 0, stream>>>();
    fin_kernel<<<1, 128, 0, stream>>>(out);
}